// Round 11
// baseline (53.969 us; speedup 1.0000x reference)
//
#include <hip/hip_runtime.h>

#define NT 256
#define NBLK 1024   // persistent grid: 4 blocks/CU x 256 CUs

typedef float f32x2 __attribute__((ext_vector_type(2)));

#if defined(__has_builtin)
#if __has_builtin(__builtin_amdgcn_exp2f)
#define EXP2F __builtin_amdgcn_exp2f
#else
#define EXP2F exp2f
#endif
#else
#define EXP2F exp2f
#endif

__device__ __forceinline__ float rfl(float x) {
    return __uint_as_float(__builtin_amdgcn_readfirstlane(__float_as_uint(x)));
}
__device__ __forceinline__ f32x2 bc2(float w) {
    f32x2 r; r.x = w; r.y = w; return r;
}
__device__ __forceinline__ f32x2 pfma(f32x2 a, f32x2 b, f32x2 c) {
    return __builtin_elementwise_fma(a, b, c);
}

// 4 sigmoids x 2 samples, reciprocal shared 4-ways per element:
// 8 exp2 + 2 rcp + ~17 packed VALU. sigmoid(a)=1/(1+exp2(-log2e*a)).
// |a|<~20 -> all intermediates < 2^88: no overflow/NaN. rel-err ~2e-6.
__device__ __forceinline__ void sig4(f32x2 v[4]) {
    const f32x2 C   = bc2(-1.442695040888963f);
    const f32x2 ONE = bc2(1.0f);
    f32x2 d[4];
    #pragma unroll
    for (int h = 0; h < 4; h++) {
        f32x2 m = v[h] * C;
        f32x2 e; e.x = EXP2F(m.x); e.y = EXP2F(m.y);
        d[h] = e + ONE;
    }
    f32x2 p01 = d[0] * d[1];
    f32x2 p23 = d[2] * d[3];
    f32x2 P   = p01 * p23;
    f32x2 r;
    r.x = __builtin_amdgcn_rcpf(P.x);
    r.y = __builtin_amdgcn_rcpf(P.y);
    f32x2 r01 = r * p23;
    f32x2 r23 = r * p01;
    v[0] = r01 * d[1];
    v[1] = r01 * d[0];
    v[2] = r23 * d[3];
    v[3] = r23 * d[2];
}

__global__ __launch_bounds__(NT, 4)
void mlp6_gs(const float* __restrict__ xl,
             const float* __restrict__ yl,
             const float* __restrict__ xr,
             const float* __restrict__ W1, const float* __restrict__ b1,
             const float* __restrict__ W2, const float* __restrict__ b2,
             const float* __restrict__ W3_2, const float* __restrict__ b3_2,
             const float* __restrict__ W3_1, const float* __restrict__ b3_1,
             const float* __restrict__ W4, const float* __restrict__ b4,
             float* __restrict__ out, int nq)
{
    // ---- loop-invariant: fold fc3(+fc4) + biases (uniform, hoisted) ----
    // W3_2 flat [4][2][4] rows j=0..3 <-> branches {0,1,4,5}; W4 flat [2][1][4];
    // W3_1 flat [2][1][4]; b3_2 flat [4][2]; b3_1 flat [2][1]; b4 flat [2][1].
    float fw[6][4];
    #pragma unroll
    for (int h = 0; h < 4; h++) {
        fw[0][h] = rfl(fmaf(W4[1], W3_2[4 + h],  W4[0] * W3_2[h]));
        fw[1][h] = rfl(fmaf(W4[5], W3_2[12 + h], W4[4] * W3_2[8 + h]));
        fw[2][h] = rfl(W3_1[h]);
        fw[3][h] = rfl(W3_1[4 + h]);
        fw[4][h] = rfl(fmaf(W4[3], W3_2[20 + h], W4[2] * W3_2[16 + h]));
        fw[5][h] = rfl(fmaf(W4[7], W3_2[28 + h], W4[6] * W3_2[24 + h]));
    }
    const float fb0 = rfl(b3_1[0]);
    const float fb1 = rfl(b3_1[1]);
    const float fb2 = rfl(W4[0]*b3_2[0] + W4[1]*b3_2[1] + W4[2]*b3_2[4] + W4[3]*b3_2[5] + b4[0]);
    const float fb3 = rfl(W4[4]*b3_2[2] + W4[5]*b3_2[3] + W4[6]*b3_2[6] + W4[7]*b3_2[7] + b4[1]);

    const int stride = NBLK * NT;

    // one branch over a sample pair; weights via uniform scalar loads
    // (loop-invariant too — compiler keeps them in SGPRs across iterations)
    auto br = [&](int k, const f32x2 (&in)[5], const float fwk[4], f32x2& oslot) {
        f32x2 h[4];
        #pragma unroll
        for (int hh = 0; hh < 4; hh++) {
            f32x2 acc = pfma(in[0], bc2(W1[k*20 + hh*5]), bc2(b1[k*4 + hh]));
            #pragma unroll
            for (int q = 1; q < 5; q++)
                acc = pfma(in[q], bc2(W1[k*20 + hh*5 + q]), acc);
            h[hh] = acc;
        }
        sig4(h);
        f32x2 c[4];
        #pragma unroll
        for (int g = 0; g < 4; g++) {
            f32x2 acc = pfma(h[0], bc2(W2[k*16 + g*4]), bc2(b2[k*4 + g]));
            #pragma unroll
            for (int q = 1; q < 4; q++)
                acc = pfma(h[q], bc2(W2[k*16 + g*4 + q]), acc);
            c[g] = acc;
        }
        sig4(c);
        #pragma unroll
        for (int g = 0; g < 4; g++) oslot = pfma(c[g], bc2(fwk[g]), oslot);
    };

    for (int gq = blockIdx.x * NT + threadIdx.x; gq < nq; gq += stride) {
        // ---- load 2 samples x 5 feats per array as 5x dwordx2 ----
        f32x2 LA[5], LB[5], LC[5];
        {
            const f32x2* x2 = (const f32x2*)xl + (long long)gq * 5;
            const f32x2* y2 = (const f32x2*)yl + (long long)gq * 5;
            const f32x2* c2 = (const f32x2*)xr + (long long)gq * 5;
            #pragma unroll
            for (int q = 0; q < 5; q++) LA[q] = x2[q];
            #pragma unroll
            for (int q = 0; q < 5; q++) LB[q] = y2[q];
            #pragma unroll
            for (int q = 0; q < 5; q++) LC[q] = c2[q];
        }
        // repack to per-feature sample-pairs
        f32x2 xp[5], yp[5], cp[5];
        xp[0].x = LA[0].x; xp[0].y = LA[2].y;
        xp[1].x = LA[0].y; xp[1].y = LA[3].x;
        xp[2].x = LA[1].x; xp[2].y = LA[3].y;
        xp[3].x = LA[1].y; xp[3].y = LA[4].x;
        xp[4].x = LA[2].x; xp[4].y = LA[4].y;
        yp[0].x = LB[0].x; yp[0].y = LB[2].y;
        yp[1].x = LB[0].y; yp[1].y = LB[3].x;
        yp[2].x = LB[1].x; yp[2].y = LB[3].y;
        yp[3].x = LB[1].y; yp[3].y = LB[4].x;
        yp[4].x = LB[2].x; yp[4].y = LB[4].y;
        cp[0].x = LC[0].x; cp[0].y = LC[2].y;
        cp[1].x = LC[0].y; cp[1].y = LC[3].x;
        cp[2].x = LC[1].x; cp[2].y = LC[3].y;
        cp[3].x = LC[1].y; cp[3].y = LC[4].x;
        cp[4].x = LC[2].x; cp[4].y = LC[4].y;

        f32x2 o0 = bc2(fb0), o1 = bc2(fb1), o2 = bc2(fb2), o3 = bc2(fb3);

        // X = stack([xl, yl, xr, yl, xl, yl]);
        // slots: br2->o0, br3->o1, {br0,br4}->o2, {br1,br5}->o3
        br(0, xp, fw[0], o2);
        br(4, xp, fw[4], o2);
        br(1, yp, fw[1], o3);
        br(3, yp, fw[3], o1);
        br(5, yp, fw[5], o3);
        br(2, cp, fw[2], o0);

        float4 r0, r1;
        r0.x = o0.x; r0.y = o1.x; r0.z = o2.x; r0.w = o3.x;
        r1.x = o0.y; r1.y = o1.y; r1.z = o2.y; r1.w = o3.y;
        float4* out4 = (float4*)out + (long long)gq * 2;
        out4[0] = r0;
        out4[1] = r1;
    }
}

extern "C" void kernel_launch(void* const* d_in, const int* in_sizes, int n_in,
                              void* d_out, int out_size, void* d_ws, size_t ws_size,
                              hipStream_t stream) {
    const float* xl   = (const float*)d_in[0];
    const float* yl   = (const float*)d_in[1];
    const float* xr   = (const float*)d_in[2];
    // d_in[3] = yr — unused by the reference forward
    const float* W1   = (const float*)d_in[4];
    const float* b1   = (const float*)d_in[5];
    const float* W2   = (const float*)d_in[6];
    const float* b2   = (const float*)d_in[7];
    const float* W3_2 = (const float*)d_in[8];
    const float* b3_2 = (const float*)d_in[9];
    const float* W3_1 = (const float*)d_in[10];
    const float* b3_1 = (const float*)d_in[11];
    const float* W4   = (const float*)d_in[12];
    const float* b4   = (const float*)d_in[13];
    float* out = (float*)d_out;

    int B  = in_sizes[0] / 5;              // 2,000,000 (even)
    int nq = B >> 1;                       // 1,000,000 sample pairs
    int blocks = (nq + NT - 1) / NT;
    if (blocks > NBLK) blocks = NBLK;      // persistent grid-stride
    mlp6_gs<<<blocks, NT, 0, stream>>>(
        xl, yl, xr, W1, b1, W2, b2, W3_2, b3_2, W3_1, b3_1, W4, b4, out, nq);
}

// Round 12
// 39.276 us; speedup vs baseline: 1.3741x; 1.3741x over previous
//
#include <hip/hip_runtime.h>

#define NT 256

typedef float f32x2 __attribute__((ext_vector_type(2)));

#if defined(__has_builtin)
#if __has_builtin(__builtin_amdgcn_exp2f)
#define EXP2F __builtin_amdgcn_exp2f
#else
#define EXP2F exp2f
#endif
#else
#define EXP2F exp2f
#endif

__device__ __forceinline__ f32x2 bc2(float w) {
    f32x2 r; r.x = w; r.y = w; return r;
}
__device__ __forceinline__ f32x2 pfma(f32x2 a, f32x2 b, f32x2 c) {
    return __builtin_elementwise_fma(a, b, c);
}

// ws layout (floats):
//   [0..119]   W1' = C*W1          (C = -log2(e))
//   [120..143] b1' = C*b1
//   [144..239] W2' = C*W2
//   [240..263] b2' = C*b2
//   [264..287] fw[6][4]  (fc3(+fc4) folded per-branch 4-vec)
//   [288..291] fb[4]     (folded output biases)
#define WS_W1 0
#define WS_B1 120
#define WS_W2 144
#define WS_B2 240
#define WS_FW 264
#define WS_FB 288

__global__ void mlp6_prefold(const float* __restrict__ W1, const float* __restrict__ b1,
                             const float* __restrict__ W2, const float* __restrict__ b2,
                             const float* __restrict__ W3_2, const float* __restrict__ b3_2,
                             const float* __restrict__ W3_1, const float* __restrict__ b3_1,
                             const float* __restrict__ W4, const float* __restrict__ b4,
                             float* __restrict__ ws)
{
    const float C = -1.442695040888963f;
    int t = threadIdx.x;
    if (t < 120) {
        ws[WS_W1 + t] = C * W1[t];
    } else if (t < 144) {
        ws[WS_B1 + (t - 120)] = C * b1[t - 120];
    } else if (t < 240) {
        ws[WS_W2 + (t - 144)] = C * W2[t - 144];
    } else if (t < 264) {
        ws[WS_B2 + (t - 240)] = C * b2[t - 240];
    } else if (t < 288) {
        // W3_2 flat [4][2][4] rows j=0..3 <-> branches {0,1,4,5}; W4 flat [2][1][4];
        // W3_1 flat [2][1][4].
        int q = t - 264, k = q >> 2, h = q & 3;
        float v;
        if (k == 0)      v = W4[0]*W3_2[h]      + W4[1]*W3_2[4 + h];
        else if (k == 1) v = W4[4]*W3_2[8 + h]  + W4[5]*W3_2[12 + h];
        else if (k == 2) v = W3_1[h];
        else if (k == 3) v = W3_1[4 + h];
        else if (k == 4) v = W4[2]*W3_2[16 + h] + W4[3]*W3_2[20 + h];
        else             v = W4[6]*W3_2[24 + h] + W4[7]*W3_2[28 + h];
        ws[WS_FW + q] = v;
    } else if (t < 292) {
        int j = t - 288;
        float v;
        if (j == 0)      v = b3_1[0];
        else if (j == 1) v = b3_1[1];
        else if (j == 2) v = W4[0]*b3_2[0] + W4[1]*b3_2[1] + W4[2]*b3_2[4] + W4[3]*b3_2[5] + b4[0];
        else             v = W4[4]*b3_2[2] + W4[5]*b3_2[3] + W4[6]*b3_2[6] + W4[7]*b3_2[7] + b4[1];
        ws[WS_FB + j] = v;
    }
}

// 4 sigmoids x 2 samples; preactivations arrive PRE-SCALED by -log2(e), so
// no input mul: d = 1+exp2(v). Reciprocal shared 4-ways per element:
// 8 exp2 + 2 rcp + ~13 packed VALU. |v| <~ 30 -> intermediates < 2^88: safe.
__device__ __forceinline__ void sig4(f32x2 v[4]) {
    const f32x2 ONE = bc2(1.0f);
    f32x2 d[4];
    #pragma unroll
    for (int h = 0; h < 4; h++) {
        f32x2 e; e.x = EXP2F(v[h].x); e.y = EXP2F(v[h].y);
        d[h] = e + ONE;
    }
    f32x2 p01 = d[0] * d[1];
    f32x2 p23 = d[2] * d[3];
    f32x2 P   = p01 * p23;
    f32x2 r;
    r.x = __builtin_amdgcn_rcpf(P.x);
    r.y = __builtin_amdgcn_rcpf(P.y);
    f32x2 r01 = r * p23;
    f32x2 r23 = r * p01;
    v[0] = r01 * d[1];
    v[1] = r01 * d[0];
    v[2] = r23 * d[3];
    v[3] = r23 * d[2];
}

__global__ __launch_bounds__(NT, 4)
void mlp6_fused(const float* __restrict__ xl,
                const float* __restrict__ yl,
                const float* __restrict__ xr,
                const float* __restrict__ ws,
                float* __restrict__ out, int nq)
{
    int gq = blockIdx.x * NT + threadIdx.x;
    if (gq >= nq) gq = nq - 1;                 // clamped dup-writes are identical

    // ---- load 2 samples x 5 feats per array as 5x dwordx2 (8B-aligned) ----
    f32x2 LA[5], LB[5], LC[5];
    {
        const f32x2* x2 = (const f32x2*)xl + (long long)gq * 5;
        const f32x2* y2 = (const f32x2*)yl + (long long)gq * 5;
        const f32x2* c2 = (const f32x2*)xr + (long long)gq * 5;
        #pragma unroll
        for (int q = 0; q < 5; q++) LA[q] = x2[q];
        #pragma unroll
        for (int q = 0; q < 5; q++) LB[q] = y2[q];
        #pragma unroll
        for (int q = 0; q < 5; q++) LC[q] = c2[q];
    }
    // repack to per-feature sample-pairs: xp[q] = {x[s0][q], x[s1][q]}
    f32x2 xp[5], yp[5];
    xp[0].x = LA[0].x; xp[0].y = LA[2].y;
    xp[1].x = LA[0].y; xp[1].y = LA[3].x;
    xp[2].x = LA[1].x; xp[2].y = LA[3].y;
    xp[3].x = LA[1].y; xp[3].y = LA[4].x;
    xp[4].x = LA[2].x; xp[4].y = LA[4].y;
    yp[0].x = LB[0].x; yp[0].y = LB[2].y;
    yp[1].x = LB[0].y; yp[1].y = LB[3].x;
    yp[2].x = LB[1].x; yp[2].y = LB[3].y;
    yp[3].x = LB[1].y; yp[3].y = LB[4].x;
    yp[4].x = LB[2].x; yp[4].y = LB[4].y;

    const float* wW1 = ws + WS_W1;
    const float* wb1 = ws + WS_B1;
    const float* wW2 = ws + WS_W2;
    const float* wb2 = ws + WS_B2;
    const float* wfw = ws + WS_FW;
    const float* wfb = ws + WS_FB;

    f32x2 o0 = bc2(wfb[0]), o1 = bc2(wfb[1]), o2 = bc2(wfb[2]), o3 = bc2(wfb[3]);

    // ---- one branch over a sample pair; C-prescaled weights from ws ----
    auto br = [&](int k, const f32x2 (&in)[5], f32x2& oslot) {
        f32x2 h[4];
        #pragma unroll
        for (int hh = 0; hh < 4; hh++) {
            f32x2 acc = pfma(in[0], bc2(wW1[k*20 + hh*5]), bc2(wb1[k*4 + hh]));
            #pragma unroll
            for (int q = 1; q < 5; q++)
                acc = pfma(in[q], bc2(wW1[k*20 + hh*5 + q]), acc);
            h[hh] = acc;
        }
        sig4(h);
        f32x2 c[4];
        #pragma unroll
        for (int g = 0; g < 4; g++) {
            f32x2 acc = pfma(h[0], bc2(wW2[k*16 + g*4]), bc2(wb2[k*4 + g]));
            #pragma unroll
            for (int q = 1; q < 4; q++)
                acc = pfma(h[q], bc2(wW2[k*16 + g*4 + q]), acc);
            c[g] = acc;
        }
        sig4(c);
        #pragma unroll
        for (int g = 0; g < 4; g++) oslot = pfma(c[g], bc2(wfw[k*4 + g]), oslot);
    };

    // X = stack([xl, yl, xr, yl, xl, yl]); slots: br2->o0, br3->o1,
    // {br0,br4}->o2, {br1,br5}->o3
    br(0, xp, o2);
    br(4, xp, o2);
    // xl consumed -> repack xr into xp (LC loaded up top, long since landed)
    xp[0].x = LC[0].x; xp[0].y = LC[2].y;
    xp[1].x = LC[0].y; xp[1].y = LC[3].x;
    xp[2].x = LC[1].x; xp[2].y = LC[3].y;
    xp[3].x = LC[1].y; xp[3].y = LC[4].x;
    xp[4].x = LC[2].x; xp[4].y = LC[4].y;
    br(1, yp, o3);
    br(3, yp, o1);
    br(5, yp, o3);
    br(2, xp, o0);

    float4 r0, r1;
    r0.x = o0.x; r0.y = o1.x; r0.z = o2.x; r0.w = o3.x;
    r1.x = o0.y; r1.y = o1.y; r1.z = o2.y; r1.w = o3.y;
    float4* out4 = (float4*)out;
    out4[(long long)gq * 2]     = r0;   // lane-consecutive 32B: fully coalesced
    out4[(long long)gq * 2 + 1] = r1;
}

extern "C" void kernel_launch(void* const* d_in, const int* in_sizes, int n_in,
                              void* d_out, int out_size, void* d_ws, size_t ws_size,
                              hipStream_t stream) {
    const float* xl   = (const float*)d_in[0];
    const float* yl   = (const float*)d_in[1];
    const float* xr   = (const float*)d_in[2];
    // d_in[3] = yr — unused by the reference forward
    const float* W1   = (const float*)d_in[4];
    const float* b1   = (const float*)d_in[5];
    const float* W2   = (const float*)d_in[6];
    const float* b2   = (const float*)d_in[7];
    const float* W3_2 = (const float*)d_in[8];
    const float* b3_2 = (const float*)d_in[9];
    const float* W3_1 = (const float*)d_in[10];
    const float* b3_1 = (const float*)d_in[11];
    const float* W4   = (const float*)d_in[12];
    const float* b4   = (const float*)d_in[13];
    float* out = (float*)d_out;
    float* ws  = (float*)d_ws;

    mlp6_prefold<<<1, 320, 0, stream>>>(
        W1, b1, W2, b2, W3_2, b3_2, W3_1, b3_1, W4, b4, ws);

    int B  = in_sizes[0] / 5;              // 2,000,000 (even)
    int nq = B >> 1;                       // sample pairs
    int blocks = (nq + NT - 1) / NT;
    mlp6_fused<<<blocks, NT, 0, stream>>>(xl, yl, xr, ws, out, nq);
}

// Round 13
// 39.007 us; speedup vs baseline: 1.3836x; 1.0069x over previous
//
#include <hip/hip_runtime.h>

#define NT 256

typedef float f32x2 __attribute__((ext_vector_type(2)));

#if defined(__has_builtin)
#if __has_builtin(__builtin_amdgcn_exp2f)
#define EXP2F __builtin_amdgcn_exp2f
#else
#define EXP2F exp2f
#endif
#else
#define EXP2F exp2f
#endif

__device__ __forceinline__ f32x2 bc2(float w) {
    f32x2 r; r.x = w; r.y = w; return r;
}
__device__ __forceinline__ f32x2 pfma(f32x2 a, f32x2 b, f32x2 c) {
    return __builtin_elementwise_fma(a, b, c);
}

// ws layout (floats):
//   [0..119]   W1' = C*W1          (C = -log2(e))
//   [120..143] b1' = C*b1
//   [144..239] W2' = C*W2
//   [240..263] b2' = C*b2
//   [264..287] fw[6][4]  (fc3(+fc4) folded per-branch 4-vec)
//   [288..291] fb[4]     (folded output biases)
#define WS_W1 0
#define WS_B1 120
#define WS_W2 144
#define WS_B2 240
#define WS_FW 264
#define WS_FB 288

__global__ void mlp6_prefold(const float* __restrict__ W1, const float* __restrict__ b1,
                             const float* __restrict__ W2, const float* __restrict__ b2,
                             const float* __restrict__ W3_2, const float* __restrict__ b3_2,
                             const float* __restrict__ W3_1, const float* __restrict__ b3_1,
                             const float* __restrict__ W4, const float* __restrict__ b4,
                             float* __restrict__ ws)
{
    const float C = -1.442695040888963f;
    int t = threadIdx.x;
    if (t < 120) {
        ws[WS_W1 + t] = C * W1[t];
    } else if (t < 144) {
        ws[WS_B1 + (t - 120)] = C * b1[t - 120];
    } else if (t < 240) {
        ws[WS_W2 + (t - 144)] = C * W2[t - 144];
    } else if (t < 264) {
        ws[WS_B2 + (t - 240)] = C * b2[t - 240];
    } else if (t < 288) {
        // W3_2 flat [4][2][4] rows j=0..3 <-> branches {0,1,4,5}; W4 flat [2][1][4];
        // W3_1 flat [2][1][4].
        int q = t - 264, k = q >> 2, h = q & 3;
        float v;
        if (k == 0)      v = W4[0]*W3_2[h]      + W4[1]*W3_2[4 + h];
        else if (k == 1) v = W4[4]*W3_2[8 + h]  + W4[5]*W3_2[12 + h];
        else if (k == 2) v = W3_1[h];
        else if (k == 3) v = W3_1[4 + h];
        else if (k == 4) v = W4[2]*W3_2[16 + h] + W4[3]*W3_2[20 + h];
        else             v = W4[6]*W3_2[24 + h] + W4[7]*W3_2[28 + h];
        ws[WS_FW + q] = v;
    } else if (t < 292) {
        int j = t - 288;
        float v;
        if (j == 0)      v = b3_1[0];
        else if (j == 1) v = b3_1[1];
        else if (j == 2) v = W4[0]*b3_2[0] + W4[1]*b3_2[1] + W4[2]*b3_2[4] + W4[3]*b3_2[5] + b4[0];
        else             v = W4[4]*b3_2[2] + W4[5]*b3_2[3] + W4[6]*b3_2[6] + W4[7]*b3_2[7] + b4[1];
        ws[WS_FB + j] = v;
    }
}

// per-element sigmoid, preactivation PRE-SCALED by -log2(e):
// sigma = rcp(1 + exp2(v)). 3-op dependent chain, no cross-element coupling.
__device__ __forceinline__ f32x2 sig2(f32x2 v) {
    f32x2 e;
    e.x = EXP2F(v.x);
    e.y = EXP2F(v.y);
    f32x2 d = e + bc2(1.0f);
    f32x2 r;
    r.x = __builtin_amdgcn_rcpf(d.x);
    r.y = __builtin_amdgcn_rcpf(d.y);
    return r;
}

__global__ __launch_bounds__(NT, 3)
void mlp6_fused(const float* __restrict__ xl,
                const float* __restrict__ yl,
                const float* __restrict__ xr,
                const float* __restrict__ ws,
                float* __restrict__ out, int nq)
{
    int gq = blockIdx.x * NT + threadIdx.x;
    if (gq >= nq) gq = nq - 1;                 // clamped dup-writes are identical

    // ---- load 2 samples x 5 feats per array as 5x dwordx2 (8B-aligned) ----
    f32x2 LA[5], LB[5], LC[5];
    {
        const f32x2* x2 = (const f32x2*)xl + (long long)gq * 5;
        const f32x2* y2 = (const f32x2*)yl + (long long)gq * 5;
        const f32x2* c2 = (const f32x2*)xr + (long long)gq * 5;
        #pragma unroll
        for (int q = 0; q < 5; q++) LA[q] = x2[q];
        #pragma unroll
        for (int q = 0; q < 5; q++) LB[q] = y2[q];
        #pragma unroll
        for (int q = 0; q < 5; q++) LC[q] = c2[q];
    }
    // repack to per-feature sample-pairs
    f32x2 xp[5], yp[5], cp[5];
    xp[0].x = LA[0].x; xp[0].y = LA[2].y;
    xp[1].x = LA[0].y; xp[1].y = LA[3].x;
    xp[2].x = LA[1].x; xp[2].y = LA[3].y;
    xp[3].x = LA[1].y; xp[3].y = LA[4].x;
    xp[4].x = LA[2].x; xp[4].y = LA[4].y;
    yp[0].x = LB[0].x; yp[0].y = LB[2].y;
    yp[1].x = LB[0].y; yp[1].y = LB[3].x;
    yp[2].x = LB[1].x; yp[2].y = LB[3].y;
    yp[3].x = LB[1].y; yp[3].y = LB[4].x;
    yp[4].x = LB[2].x; yp[4].y = LB[4].y;
    cp[0].x = LC[0].x; cp[0].y = LC[2].y;
    cp[1].x = LC[0].y; cp[1].y = LC[3].x;
    cp[2].x = LC[1].x; cp[2].y = LC[3].y;
    cp[3].x = LC[1].y; cp[3].y = LC[4].x;
    cp[4].x = LC[2].x; cp[4].y = LC[4].y;

    const float* wW1 = ws + WS_W1;
    const float* wb1 = ws + WS_B1;
    const float* wW2 = ws + WS_W2;
    const float* wb2 = ws + WS_B2;
    const float* wfw = ws + WS_FW;
    const float* wfb = ws + WS_FB;

    f32x2 o0 = bc2(wfb[0]), o1 = bc2(wfb[1]), o2 = bc2(wfb[2]), o3 = bc2(wfb[3]);

    // ---- TWO branches processed as interleaved independent chains ----
    auto pair2 = [&](int kA, const f32x2 (&inA)[5], f32x2& oA,
                     int kB, const f32x2 (&inB)[5], f32x2& oB) {
        f32x2 hA[4], hB[4];
        #pragma unroll
        for (int hh = 0; hh < 4; hh++) {
            f32x2 aA = pfma(inA[0], bc2(wW1[kA*20 + hh*5]), bc2(wb1[kA*4 + hh]));
            f32x2 aB = pfma(inB[0], bc2(wW1[kB*20 + hh*5]), bc2(wb1[kB*4 + hh]));
            #pragma unroll
            for (int q = 1; q < 5; q++) {
                aA = pfma(inA[q], bc2(wW1[kA*20 + hh*5 + q]), aA);
                aB = pfma(inB[q], bc2(wW1[kB*20 + hh*5 + q]), aB);
            }
            hA[hh] = sig2(aA);
            hB[hh] = sig2(aB);
        }
        f32x2 cA[4], cB[4];
        #pragma unroll
        for (int g = 0; g < 4; g++) {
            f32x2 aA = pfma(hA[0], bc2(wW2[kA*16 + g*4]), bc2(wb2[kA*4 + g]));
            f32x2 aB = pfma(hB[0], bc2(wW2[kB*16 + g*4]), bc2(wb2[kB*4 + g]));
            #pragma unroll
            for (int q = 1; q < 4; q++) {
                aA = pfma(hA[q], bc2(wW2[kA*16 + g*4 + q]), aA);
                aB = pfma(hB[q], bc2(wW2[kB*16 + g*4 + q]), aB);
            }
            cA[g] = sig2(aA);
            cB[g] = sig2(aB);
        }
        #pragma unroll
        for (int g = 0; g < 4; g++) {
            oA = pfma(cA[g], bc2(wfw[kA*4 + g]), oA);
            oB = pfma(cB[g], bc2(wfw[kB*4 + g]), oB);
        }
    };

    // X = stack([xl, yl, xr, yl, xl, yl]); slots: br2->o0, br3->o1,
    // {br0,br4}->o2, {br1,br5}->o3. Pairs chosen with disjoint inputs/outputs.
    pair2(0, xp, o2, 1, yp, o3);
    pair2(4, xp, o2, 3, yp, o1);
    pair2(5, yp, o3, 2, cp, o0);

    float4 r0, r1;
    r0.x = o0.x; r0.y = o1.x; r0.z = o2.x; r0.w = o3.x;
    r1.x = o0.y; r1.y = o1.y; r1.z = o2.y; r1.w = o3.y;
    float4* out4 = (float4*)out;
    out4[(long long)gq * 2]     = r0;   // lane-consecutive 32B: fully coalesced
    out4[(long long)gq * 2 + 1] = r1;
}

extern "C" void kernel_launch(void* const* d_in, const int* in_sizes, int n_in,
                              void* d_out, int out_size, void* d_ws, size_t ws_size,
                              hipStream_t stream) {
    const float* xl   = (const float*)d_in[0];
    const float* yl   = (const float*)d_in[1];
    const float* xr   = (const float*)d_in[2];
    // d_in[3] = yr — unused by the reference forward
    const float* W1   = (const float*)d_in[4];
    const float* b1   = (const float*)d_in[5];
    const float* W2   = (const float*)d_in[6];
    const float* b2   = (const float*)d_in[7];
    const float* W3_2 = (const float*)d_in[8];
    const float* b3_2 = (const float*)d_in[9];
    const float* W3_1 = (const float*)d_in[10];
    const float* b3_1 = (const float*)d_in[11];
    const float* W4   = (const float*)d_in[12];
    const float* b4   = (const float*)d_in[13];
    float* out = (float*)d_out;
    float* ws  = (float*)d_ws;

    mlp6_prefold<<<1, 320, 0, stream>>>(
        W1, b1, W2, b2, W3_2, b3_2, W3_1, b3_1, W4, b4, ws);

    int B  = in_sizes[0] / 5;              // 2,000,000 (even)
    int nq = B >> 1;                       // sample pairs
    int blocks = (nq + NT - 1) / NT;
    mlp6_fused<<<blocks, NT, 0, stream>>>(xl, yl, xr, ws, out, nq);
}